// Round 8
// baseline (101.525 us; speedup 1.0000x reference)
//
#include <hip/hip_runtime.h>

#define B_  16
#define LQ  256
#define LK  256
#define QD  256
#define HD  128
#define VD  128

// 2*log2(e): exp2(SCALE2*x) = e^{2x}
#define SCALE2 2.8853900817779268f
#define CTX_SIZE (B_ * LK * VD)

typedef float v2f __attribute__((ext_vector_type(2)));
typedef float v4f __attribute__((ext_vector_type(4)));

__device__ __forceinline__ float fast_exp2(float x) { return __builtin_amdgcn_exp2f(x); }
__device__ __forceinline__ float fast_rcp(float x)  { return __builtin_amdgcn_rcpf(x); }

// ---------------------------------------------------------------------------
// proj_kernel: 1024 blocks x 256 threads (unchanged — known-good).
//   blocks [0,512):   qe4[b][h/4][q][4] = exp2(SCALE2 * (query @ Wq))
//   blocks [512,1024): ke[b][k][h]  = exp2(SCALE2 * (key @ Wk))
// ---------------------------------------------------------------------------
__global__ __launch_bounds__(256) void proj_kernel(const float* __restrict__ query,
                                                   const float* __restrict__ key,
                                                   const float* __restrict__ Wq,
                                                   const float* __restrict__ Wk,
                                                   float* __restrict__ qe_t,
                                                   float* __restrict__ ke)
{
    __shared__ float  Xs[8][260];        // 8 rows x full K (=256), padded
    __shared__ float4 part[4][8][32];    // [wave][m][h-group] partial sums

    const int t = threadIdx.x;
    const bool isQ = (blockIdx.x < 512);
    const int blk  = isQ ? blockIdx.x : (blockIdx.x - 512);
    const int rows0 = blk * 8;
    const float* X = isQ ? query : key;
    const float* W = isQ ? Wq : Wk;

    // ---- stage X tile: 8 rows x 256 k (8 KB) ----
    {
        const int r = t >> 5;            // 0..7
        const int c = (t & 31) * 8;      // 0..248
        const float4 x0 = *(const float4*)(X + (size_t)(rows0 + r) * QD + c);
        const float4 x1 = *(const float4*)(X + (size_t)(rows0 + r) * QD + c + 4);
        *(float4*)&Xs[r][c]     = x0;
        *(float4*)&Xs[r][c + 4] = x1;
    }
    __syncthreads();

    const int w    = t >> 6;
    const int lane = t & 63;
    const int hg   = lane & 31;          // h4 = hg*4
    const int mb   = lane >> 5;          // 0/1; lane covers m = mb, mb+2, mb+4, mb+6

    float4 acc[4];
#pragma unroll
    for (int i = 0; i < 4; i++) acc[i] = make_float4(0.f, 0.f, 0.f, 0.f);

    const int kbase = w * 64;
#pragma unroll 4
    for (int kk = 0; kk < 64; kk++) {
        const int k = kbase + kk;
        const float4 wv = *(const float4*)(W + (size_t)k * HD + hg * 4);
#pragma unroll
        for (int mi = 0; mi < 4; mi++) {
            const float xv = Xs[mb + mi * 2][k];
            acc[mi].x += xv * wv.x;
            acc[mi].y += xv * wv.y;
            acc[mi].z += xv * wv.z;
            acc[mi].w += xv * wv.w;
        }
    }
#pragma unroll
    for (int mi = 0; mi < 4; mi++) part[w][mb + mi * 2][hg] = acc[mi];
    __syncthreads();

    // ---- reduce 4 partials, exp, store ----
    {
        const int m   = t >> 5;          // 0..7
        const int hg2 = t & 31;          // 0..31  (covers h = hg2*4 .. +3)
        float4 s = part[0][m][hg2];
        const float4 p1 = part[1][m][hg2];
        const float4 p2 = part[2][m][hg2];
        const float4 p3 = part[3][m][hg2];
        s.x += p1.x + p2.x + p3.x;
        s.y += p1.y + p2.y + p3.y;
        s.z += p1.z + p2.z + p3.z;
        s.w += p1.w + p2.w + p3.w;
        float4 e = make_float4(fast_exp2(s.x * SCALE2), fast_exp2(s.y * SCALE2),
                               fast_exp2(s.z * SCALE2), fast_exp2(s.w * SCALE2));
        const int row = rows0 + m;
        if (isQ) {
            const int b = row >> 8, q = row & 255;
            // qe4 layout: [b][h4 = hg2][q][4] — single coalesced 16B store
            *(float4*)(qe_t + ((size_t)(b * 32 + hg2) * 256 + q) * 4) = e;
        } else {
            *(float4*)(ke + (size_t)row * HD + hg2 * 4) = e;
        }
    }
}

// ---------------------------------------------------------------------------
// attn_kernel v8: 1024 blocks x 256 threads. Block = (b, 4 consecutive k).
//  - SOFTWARE-PIPELINED phase 1: qv[g+1] global load issued BEFORE the
//    PAIR_STEPs on qv[g] (2-deep, named regs — no dynamic indexing).
//    Theory: at VGPR~52 the compiler serialized load->vmcnt(0)->compute per
//    g-iter; ~200cy L2 latency x 32 iters was the ~2x gap over the VALU
//    floor that survived occupancy/VMEM-count/rcp-count changes (v3..v7).
//  - Paired reciprocals, min-softmax, qe4 layout, LDS ke/v, f4 phase 3 kept.
// ---------------------------------------------------------------------------
__global__ __launch_bounds__(256) void attn_kernel(const float* __restrict__ qe_t,
                                                   const float* __restrict__ ke,
                                                   const float* __restrict__ v,
                                                   const float* __restrict__ value,
                                                   float* __restrict__ out)
{
    __shared__ float ke_s[4][128];        // 2 KB   e^{2kp} rows k0..k0+3
    __shared__ float v_s[128];            // 0.5 KB
    __shared__ float score_s[4][260];     // 4.1 KB
    __shared__ float attn_T[256][4];      // 4 KB  [q][k]
    __shared__ v4f   partc4[4][4][2][32]; // 16 KB [wave][k][q-parity][vd4]

    const int t  = threadIdx.x;
    const int b  = blockIdx.x >> 6;
    const int k0 = (blockIdx.x & 63) << 2;

    const float* qeb = qe_t + (size_t)b * (32 * 256 * 4);   // [h4][q][4], e^{2qp}
    const float* kep = ke + ((size_t)b * LK + k0) * HD;     // 4 rows, e^{2kp}

    // ---- stage ke + v into LDS (coalesced: 512 + 128 consecutive floats) ----
    ((float*)ke_s)[t]       = kep[t];
    ((float*)ke_s)[t + 256] = kep[t + 256];
    if (t < 128) v_s[t] = v[t];
    __syncthreads();

    // ---- Phase 1 (software-pipelined over g) ----
    float acc0 = 0.f, acc1 = 0.f, acc2 = 0.f, acc3 = 0.f;
    const int q = t;
    const float* qcol = qeb + (size_t)q * 4;   // column base; g-stride 1024 floats

#define PAIR_STEP(QJ, VJ, KA, KB, KC, KD)                          \
    {                                                              \
        const float t0 = fmaf(QJ, KA, 1.0f);                       \
        const float t1 = fmaf(QJ, KB, 1.0f);                       \
        const float t2 = fmaf(QJ, KC, 1.0f);                       \
        const float t3 = fmaf(QJ, KD, 1.0f);                       \
        const float r01 = fast_rcp(t0 * t1);                       \
        const float r23 = fast_rcp(t2 * t3);                       \
        acc0 = fmaf(VJ * t1, r01, acc0);                           \
        acc1 = fmaf(VJ * t0, r01, acc1);                           \
        acc2 = fmaf(VJ * t3, r23, acc2);                           \
        acc3 = fmaf(VJ * t2, r23, acc3);                           \
    }

#define COMPUTE_G(QV, G)                                           \
    {                                                              \
        const int hA = (G) * 4;                                    \
        const float4 va = *(const float4*)&v_s[hA];                \
        const float4 ka = *(const float4*)&ke_s[0][hA];            \
        const float4 kb = *(const float4*)&ke_s[1][hA];            \
        const float4 kc = *(const float4*)&ke_s[2][hA];            \
        const float4 kd = *(const float4*)&ke_s[3][hA];            \
        PAIR_STEP(QV.x, va.x, ka.x, kb.x, kc.x, kd.x)              \
        PAIR_STEP(QV.y, va.y, ka.y, kb.y, kc.y, kd.y)              \
        PAIR_STEP(QV.z, va.z, ka.z, kb.z, kc.z, kd.z)              \
        PAIR_STEP(QV.w, va.w, ka.w, kb.w, kc.w, kd.w)              \
    }

    // 2-deep pipeline: A holds even g, B holds odd g. Loads issued one
    // iteration ahead of use; named regs keep indexing static.
    float4 qvA = *(const float4*)(qcol + 0 * 1024);
    float4 qvB = *(const float4*)(qcol + 1 * 1024);
#pragma unroll
    for (int g = 0; g < 30; g += 2) {
        COMPUTE_G(qvA, g)
        qvA = *(const float4*)(qcol + (size_t)(g + 2) * 1024);
        COMPUTE_G(qvB, g + 1)
        qvB = *(const float4*)(qcol + (size_t)(g + 3) * 1024);
    }
    COMPUTE_G(qvA, 30)
    COMPUTE_G(qvB, 31)
#undef COMPUTE_G
#undef PAIR_STEP

    // score = sumv - 2*acc; softmax is shift-invariant -> store raw acc
    score_s[0][q] = acc0;
    score_s[1][q] = acc1;
    score_s[2][q] = acc2;
    score_s[3][q] = acc3;
    __syncthreads();

    // ---- Phase 2: softmax over q, wave w handles k=w.
    //      score = -2*acc -> max(score) == min(acc);
    //      e^{score - max} = exp2((m - acc) * SCALE2)
    const int w = t >> 6, lane = t & 63;
    {
        float x0 = score_s[w][lane];
        float x1 = score_s[w][lane + 64];
        float x2 = score_s[w][lane + 128];
        float x3 = score_s[w][lane + 192];
        float m = fminf(fminf(x0, x1), fminf(x2, x3));
#pragma unroll
        for (int off = 32; off >= 1; off >>= 1) m = fminf(m, __shfl_xor(m, off));
        float e0 = fast_exp2((m - x0) * SCALE2);
        float e1 = fast_exp2((m - x1) * SCALE2);
        float e2 = fast_exp2((m - x2) * SCALE2);
        float e3 = fast_exp2((m - x3) * SCALE2);
        float s = e0 + e1 + e2 + e3;
#pragma unroll
        for (int off = 32; off >= 1; off >>= 1) s += __shfl_xor(s, off);
        const float rs = fast_rcp(s);
        e0 *= rs; e1 *= rs; e2 *= rs; e3 *= rs;
        attn_T[lane][w]       = e0;
        attn_T[lane + 64][w]  = e1;
        attn_T[lane + 128][w] = e2;
        attn_T[lane + 192][w] = e3;
        float* ao = out + CTX_SIZE + ((size_t)(b * LK + k0 + w)) * LQ;
        ao[lane]       = e0;
        ao[lane + 64]  = e1;
        ao[lane + 128] = e2;
        ao[lane + 192] = e3;
    }
    __syncthreads();

    // ---- Phase 3: context, float4 granularity.
    //      lane -> (q-parity qo = lane>>5, vd4 slot = lane&31).
    //      Wave w covers q in [w*64,(w+1)*64): 32 iters x 2 q (by parity).
    {
        const int qo  = lane >> 5;            // 0/1
        const int vdi = lane & 31;            // float4 slot: vd = vdi*4
        const float* valb = value + (size_t)b * LQ * VD;
        v4f c0 = (v4f)0.f, c1 = (v4f)0.f, c2 = (v4f)0.f, c3 = (v4f)0.f;
#pragma unroll 4
        for (int i = 0; i < 32; i++) {
            const int q2 = (w << 6) + (i << 1) + qo;
            const v4f a  = *(const v4f*)&attn_T[q2][0];               // 2-addr broadcast
            const v4f vv = *(const v4f*)(valb + (size_t)q2 * VD + vdi * 4);
            c0 = __builtin_elementwise_fma((v4f)(a.x), vv, c0);
            c1 = __builtin_elementwise_fma((v4f)(a.y), vv, c1);
            c2 = __builtin_elementwise_fma((v4f)(a.z), vv, c2);
            c3 = __builtin_elementwise_fma((v4f)(a.w), vv, c3);
        }
        partc4[w][0][qo][vdi] = c0;
        partc4[w][1][qo][vdi] = c1;
        partc4[w][2][qo][vdi] = c2;
        partc4[w][3][qo][vdi] = c3;
    }
    __syncthreads();
    if (t < 128) {
        const int kg = t >> 5, vdj = t & 31;
        v4f s = (v4f)0.f;
#pragma unroll
        for (int ww = 0; ww < 4; ww++) {
            s += partc4[ww][kg][0][vdj];
            s += partc4[ww][kg][1][vdj];
        }
        *(v4f*)(out + ((size_t)(b * LK + k0 + kg)) * VD + vdj * 4) = s;
    }
}

extern "C" void kernel_launch(void* const* d_in, const int* in_sizes, int n_in,
                              void* d_out, int out_size, void* d_ws, size_t ws_size,
                              hipStream_t stream)
{
    const float* query = (const float*)d_in[0];
    const float* key   = (const float*)d_in[1];
    const float* value = (const float*)d_in[2];
    const float* Wq    = (const float*)d_in[3];
    const float* Wk    = (const float*)d_in[4];
    const float* v     = (const float*)d_in[5];
    float* out = (float*)d_out;

    float* qe_t = (float*)d_ws;                      // [B][HD/4][LQ][4], e^{2qp}
    float* kew  = qe_t + (size_t)B_ * HD * LQ;       // [B][LK][HD], e^{2kp}

    proj_kernel<<<dim3(1024), 256, 0, stream>>>(query, key, Wq, Wk, qe_t, kew);
    attn_kernel<<<dim3(1024), 256, 0, stream>>>(qe_t, kew, v, value, out);
}